// Round 6
// baseline (346.418 us; speedup 1.0000x reference)
//
#include <hip/hip_runtime.h>

// MapDensePoseTex, three-stage: transpose -> offsets -> windowed gather.
// tex (8,16,512,512) f32, iuv (8,3,512,512) i32, lut (24,256,256,2) f32,
// tex_res = 512. Output (8,16,512,512) f32.
//
// Round-8: gather is at a per-lane-request floor (~23 cyc/px = 4 x 16B
// requests x ~5.8 cyc, MSHR/miss-queue bound) -- R4/R5 proved line-merging
// doesn't happen and occupancy doesn't help. Leave it. This round: the
// transpose (unmeasured, <79us) gets global_load_lds width=16 staging (m97
// pattern): DMA global->LDS, no VGPR round-trip, no ds_writes. Segment
// placement keeps the proven 516-stride pad (per-instruction linearity only
// constrains each 1KB segment), so the read-out phase is byte-identical.

#define N_PARTS 24

typedef float v4f __attribute__((ext_vector_type(4)));
typedef int   v4i __attribute__((ext_vector_type(4)));

// ---------------- transpose: 4096 blocks, one (b, ty) row each -------------
// Staging via global_load_lds: wave w DMAs channels 4w..4w+3 (two 1KB
// segments each) into lds[c*516 + half*256 .. +255]; lanes contiguous.
__global__ __launch_bounds__(256) void dp_transpose_kernel(
    const float* __restrict__ tex,
    float*       __restrict__ texT)
{
    constexpr int C = 16, R = 512;
    constexpr size_t plane = (size_t)R * R;
    __shared__ float lds[16 * 516];          // 33 KB, padded rows (516)

    const int tid = blockIdx.x;              // 0..4095
    const int b  = tid >> 9;
    const int ty = tid & 511;
    const float* src = tex + (size_t)b * C * plane + (size_t)ty * R;
    const int t    = threadIdx.x;
    const int lane = t & 63;
    const int w    = t >> 6;

    #pragma unroll
    for (int s = 0; s < 8; ++s) {
        const int c    = w * 4 + (s >> 1);   // wave-uniform
        const int half = s & 1;              // wave-uniform
        // global src: per-lane, 16B each, 1KB contiguous per instruction
        const float* gsrc = src + (size_t)c * plane + half * 256 + lane * 4;
        // LDS dst: wave-uniform base, lanes fill base + lane*16 (linear)
        float* ldst = &lds[c * 516 + half * 256];
        __builtin_amdgcn_global_load_lds(
            (const __attribute__((address_space(1))) void*)gsrc,
            (__attribute__((address_space(3))) void*)ldst, 16, 0, 0);
    }
    __syncthreads();                         // drains vmcnt: DMA complete

    float* dst = texT + ((size_t)b * plane + (size_t)ty * R) * C;
    #pragma unroll
    for (int k = 0; k < 8; ++k) {
        const int f  = k * 256 + t;          // float4 id over (x, c-quad)
        const int x  = f >> 2;
        const int c0 = (f & 3) * 4;
        v4f v;
        v.x = lds[(c0 + 0) * 516 + x];       // pad 516 -> <=2-way conflicts
        v.y = lds[(c0 + 1) * 516 + x];
        v.z = lds[(c0 + 2) * 516 + x];
        v.w = lds[(c0 + 3) * 516 + x];
        __builtin_nontemporal_store(v, (v4f*)(dst + (size_t)f * 4));
    }
}

// ---------------- offsets: 2048 blocks x 256 th x 4 px ---------------------
// lut (3.1MB) stays hot per-XCD; iuv is nt-streamed so it can't evict it.
__global__ __launch_bounds__(256) void dp_offsets_kernel(
    const int*   __restrict__ iuv,
    const float* __restrict__ lut,
    int*         __restrict__ offs,
    int R)
{
    constexpr int H = 512, W = 512;
    const float scale = (float)(R - 1);
    const size_t hw = (size_t)H * W;
    const int t = blockIdx.x * blockDim.x + threadIdx.x;
    const int pix4 = t * 4;
    const int b = pix4 >> 18;
    const int p = pix4 & (int)(hw - 1);

    const size_t ibase = (size_t)b * 3 * hw + p;
    const v4i p4 = __builtin_nontemporal_load((const v4i*)(iuv + ibase));
    const v4i u4 = __builtin_nontemporal_load((const v4i*)(iuv + ibase + hw));
    const v4i v4 = __builtin_nontemporal_load((const v4i*)(iuv + ibase + 2 * hw));

    const int parts[4] = {p4.x, p4.y, p4.z, p4.w};
    const int us[4]    = {u4.x, u4.y, u4.z, u4.w};
    const int vs[4]    = {v4.x, v4.y, v4.z, v4.w};

    v4i o4;
    #pragma unroll
    for (int j = 0; j < 4; ++j) {
        int i = parts[j] - 1;
        i = i < 0 ? 0 : (i > N_PARTS - 1 ? N_PARTS - 1 : i);
        // Faithful to reference: f32 divide, clip, *255, round-half-even.
        const float fu = fminf(fmaxf((float)us[j] / 255.0f, 0.0f), 1.0f);
        const float fv = fminf(fmaxf((float)vs[j] / 255.0f, 0.0f), 1.0f);
        const int ui = (int)rintf(fu * 255.0f);
        const int vi = (int)rintf(fv * 255.0f);
        const float2 s = *(const float2*)(lut + (((size_t)i * 256 + vi) * 256 + ui) * 2);
        const int uI = (int)rintf(s.x * scale);
        const int vI = (int)rintf((1.0f - s.y) * scale);
        const int o = (parts[j] > 0) ? (vI * R + uI) : -1;
        if (j == 0) o4.x = o; else if (j == 1) o4.y = o;
        else if (j == 2) o4.z = o; else o4.w = o;
    }
    __builtin_nontemporal_store(o4, (v4i*)(offs + (size_t)b * hw + p));
}

// ---------------- gather: 2048 blocks, lane-cooperative lines --------------
// Per wave: 256 px in 4 iters of 64. Load instr (it,j): lanes 4p..4p+3 fetch
// the 4 quarters of pixel (it*64+j*16+p)'s 64B line. Wave-private LDS
// transpose slice, zero barriers. UNCHANGED from round-7 (at request floor).
__global__ __launch_bounds__(256) void dp_gatherT_kernel(
    const float* __restrict__ texT,
    const int*   __restrict__ offs,
    float*       __restrict__ out)
{
    constexpr int C = 16;
    constexpr size_t HW = 512 * 512;
    __shared__ float lds[4 * 1024];          // 16 KB: 4 waves x (16c x 64px)
    __shared__ int   olds[4 * 256];          //  4 KB: 4 waves x 256 offsets
    extern __shared__ float occupancy_pad[]; // pad to 64KB -> 2 blocks/CU

    const int b     = blockIdx.x & 7;        // XCD round-robin: batch per XCD
    const int inner = blockIdx.x >> 3;       // 0..255
    const int base  = inner * 1024;

    const int t    = threadIdx.x;
    const int lane = t & 63;
    const int wv   = t >> 6;

    const float* tb   = texT + (size_t)b * HW * C;
    const int*   obw  = offs + (size_t)b * HW + base + wv * 256;
    float*       outb = out  + (size_t)b * C * HW + base + wv * 256;
    float*       wlds = lds  + wv * 1024;
    int*         wo   = olds + wv * 256;

    // Preload this wave's 256 offsets into LDS (b128 both ways, linear).
    {
        const v4i o4 = __builtin_nontemporal_load((const v4i*)(obw + lane * 4));
        *(v4i*)&wo[lane * 4] = o4;
    }
    // Same-wave RAW on LDS: compiler inserts the lgkmcnt wait.

    const int sub = lane >> 2;               // pixel id within a 16-px group
    const int q   = lane & 3;                // which 16B quarter of the line

    // Issue ALL 16 gather instructions up-front (counted vmcnt keeps them
    // in flight; consume below waits only for what it needs).
    v4f g00,g01,g02,g03, g10,g11,g12,g13, g20,g21,g22,g23, g30,g31,g32,g33;
    int o00,o01,o02,o03, o10,o11,o12,o13, o20,o21,o22,o23, o30,o31,o32,o33;
#define DP_LOAD(IT, J, GV, OV)                                               \
    {                                                                        \
        OV = wo[(IT) * 64 + (J) * 16 + sub];                                 \
        const float* s_ = tb + (size_t)(OV >= 0 ? OV : 0) * C + q * 4;       \
        GV = *(const v4f*)s_;                                                \
    }
    DP_LOAD(0,0,g00,o00) DP_LOAD(0,1,g01,o01) DP_LOAD(0,2,g02,o02) DP_LOAD(0,3,g03,o03)
    DP_LOAD(1,0,g10,o10) DP_LOAD(1,1,g11,o11) DP_LOAD(1,2,g12,o12) DP_LOAD(1,3,g13,o13)
    DP_LOAD(2,0,g20,o20) DP_LOAD(2,1,g21,o21) DP_LOAD(2,2,g22,o22) DP_LOAD(2,3,g23,o23)
    DP_LOAD(3,0,g30,o30) DP_LOAD(3,1,g31,o31) DP_LOAD(3,2,g32,o32) DP_LOAD(3,3,g33,o33)
#undef DP_LOAD

#define DP_PUT(J, GV, OV)                                                    \
    {                                                                        \
        v4f v_ = GV;                                                         \
        if (OV < 0) v_ = 0.f;                                                \
        const int px_ = (J) * 16 + sub;                                      \
        const int c0_ = q * 4;                                               \
        wlds[(c0_ + 0) * 64 + px_] = v_.x;                                   \
        wlds[(c0_ + 1) * 64 + px_] = v_.y;                                   \
        wlds[(c0_ + 2) * 64 + px_] = v_.z;                                   \
        wlds[(c0_ + 3) * 64 + px_] = v_.w;                                   \
    }
#define DP_STORE(IT)                                                         \
    _Pragma("unroll")                                                        \
    for (int k = 0; k < 4; ++k) {                                            \
        const v4f v_ = *(const v4f*)&wlds[k * 256 + lane * 4];               \
        const int c_ = k * 4 + (lane >> 4);                                  \
        const int s_ = lane & 15;                                            \
        __builtin_nontemporal_store(                                         \
            v_, (v4f*)(outb + (size_t)c_ * HW + (IT) * 64 + s_ * 4));        \
    }

    // iter 0
    DP_PUT(0,g00,o00) DP_PUT(1,g01,o01) DP_PUT(2,g02,o02) DP_PUT(3,g03,o03)
    DP_STORE(0)
    // iter 1 (same-wave WAR on wlds: DS ops retire in order within a wave)
    DP_PUT(0,g10,o10) DP_PUT(1,g11,o11) DP_PUT(2,g12,o12) DP_PUT(3,g13,o13)
    DP_STORE(1)
    // iter 2
    DP_PUT(0,g20,o20) DP_PUT(1,g21,o21) DP_PUT(2,g22,o22) DP_PUT(3,g23,o23)
    DP_STORE(2)
    // iter 3
    DP_PUT(0,g30,o30) DP_PUT(1,g31,o31) DP_PUT(2,g32,o32) DP_PUT(3,g33,o33)
    DP_STORE(3)
#undef DP_PUT
#undef DP_STORE
}

// ---------------- fallback gather (small-R path) ---------------------------
__global__ __launch_bounds__(256) void dp_gather_kernel(
    const float* __restrict__ tex,
    const int*   __restrict__ offs,
    float*       __restrict__ out,
    int R)
{
    constexpr int C = 16, H = 512, W = 512;
    const size_t hw    = (size_t)H * W;
    const size_t plane = (size_t)R * R;

    const int bid  = blockIdx.x;
    const int xcd  = bid & 7;
    const int slot = bid >> 3;
    const int pl_local = slot >> 8;
    const int inner    = slot & 255;
    const int pidx = xcd * 16 + pl_local;
    const int b = pidx >> 4;
    const int c = pidx & 15;

    const int px = inner * 1024 + threadIdx.x * 4;

    const int4 o4 = *(const int4*)(offs + (size_t)b * hw + px);
    const float* tc = tex + ((size_t)b * C + c) * plane;

    float4 r;
    r.x = (o4.x >= 0) ? tc[o4.x] : 0.0f;
    r.y = (o4.y >= 0) ? tc[o4.y] : 0.0f;
    r.z = (o4.z >= 0) ? tc[o4.z] : 0.0f;
    r.w = (o4.w >= 0) ? tc[o4.w] : 0.0f;

    *(float4*)(out + ((size_t)b * C + c) * hw + px) = r;
}

extern "C" void kernel_launch(void* const* d_in, const int* in_sizes, int n_in,
                              void* d_out, int out_size, void* d_ws, size_t ws_size,
                              hipStream_t stream) {
    const float* tex = (const float*)d_in[0];
    const int*   iuv = (const int*)d_in[1];
    const float* lut = (const float*)d_in[2];
    float*       out = (float*)d_out;

    constexpr int B = 8, C = 16, H = 512, W = 512;
    int R = 512;
    {
        long long pe = (long long)in_sizes[0] / (B * C);
        int r = 1; while ((long long)(r + 1) * (r + 1) <= pe) ++r;
        R = r;
    }

    const size_t texT_bytes = (size_t)B * R * R * C * sizeof(float);  // 134 MB
    const size_t offs_bytes = (size_t)B * H * W * sizeof(int);        //   8 MB

    if (R == 512 && ws_size >= texT_bytes + offs_bytes) {
        float* texT = (float*)d_ws;
        int*   offs = (int*)((char*)d_ws + texT_bytes);
        dp_transpose_kernel<<<dim3(4096), dim3(256), 0, stream>>>(tex, texT);
        dp_offsets_kernel<<<dim3(B * H * W / 4 / 256), dim3(256), 0, stream>>>(
            iuv, lut, offs, R);
        // static LDS = 20KB; +44KB pad -> 64KB -> 2 blocks/CU (L2 window)
        dp_gatherT_kernel<<<dim3(2048), dim3(256), 45056, stream>>>(
            texT, offs, out);
    } else if (ws_size >= offs_bytes) {
        int* offs = (int*)d_ws;
        dp_offsets_kernel<<<dim3(B * H * W / 4 / 256), dim3(256), 0, stream>>>(
            iuv, lut, offs, R);
        dp_gather_kernel<<<dim3(B * C * (H * W / 1024)), dim3(256), 0, stream>>>(
            tex, offs, out, R);
    }
}